// Round 12
// baseline (260.151 us; speedup 1.0000x reference)
//
#include <hip/hip_runtime.h>
#include <hip/hip_bf16.h>

using u16 = unsigned short;
using u32 = unsigned int;

constexpr int S_LEN = 2048, BATCH = 2, EMB = 1024, NHEAD = 16, HDIM = 64, FFN_DIM = 4096;
constexpr int NTOK = S_LEN * BATCH;
constexpr int QKV_N = 3 * EMB;  // 3072
// q pre-scale: 1/sqrt(64) * log2(e)  (softmax computed in exp2 domain)
#define QSCALE 0.18033688011112042f

typedef __attribute__((ext_vector_type(4))) float f32x4;
typedef __attribute__((ext_vector_type(8))) short short8;
typedef __attribute__((ext_vector_type(8))) __bf16 bf16x8;
typedef __attribute__((ext_vector_type(8))) u16 ushort8;
typedef __attribute__((ext_vector_type(4))) u16 u16x4;

typedef const __attribute__((address_space(1))) u16 gu16;
typedef __attribute__((address_space(3))) u16 lu16;

__device__ __forceinline__ u16 f2bf(float f) {
  u32 u = __builtin_bit_cast(u32, f);
  u32 r = u + 0x7fffu + ((u >> 16) & 1u);
  return (u16)(r >> 16);
}
__device__ __forceinline__ float bf2f(u16 u) {
  return __builtin_bit_cast(float, (u32)u << 16);
}

__device__ __forceinline__ f32x4 mfma16(short8 a, short8 b, f32x4 c) {
  return __builtin_amdgcn_mfma_f32_16x16x32_bf16(
      __builtin_bit_cast(bf16x8, a), __builtin_bit_cast(bf16x8, b), c, 0, 0, 0);
}

__device__ __forceinline__ void gload16(const u16* g, u16* l) {
  __builtin_amdgcn_global_load_lds((gu16*)g, (lu16*)l, 16, 0, 0);
}

__device__ __forceinline__ u32 cvtpk(float lo, float hi) {
  u32 r;
  asm("v_cvt_pk_bf16_f32 %0, %1, %2" : "=v"(r) : "v"(lo), "v"(hi));
  return r;
}

// ---------------- fp32 -> bf16 elementwise ----------------
__global__ __launch_bounds__(256) void k_cvt_bf16(const float* __restrict__ in,
                                                  u16* __restrict__ out, int n) {
  int i = (blockIdx.x * 256 + threadIdx.x) * 8;
  if (i >= n) return;
  float4 a = *(const float4*)(in + i);
  float4 b = *(const float4*)(in + i + 4);
  ushort8 o;
  o[0] = f2bf(a.x); o[1] = f2bf(a.y); o[2] = f2bf(a.z); o[3] = f2bf(a.w);
  o[4] = f2bf(b.x); o[5] = f2bf(b.y); o[6] = f2bf(b.z); o[7] = f2bf(b.w);
  *(ushort8*)(out + i) = o;
}

// ---------------- fp32 [R][C] -> bf16 [C][R] (weight transpose, optional scale) ----
__global__ __launch_bounds__(256) void k_transpose_w(const float* __restrict__ in,
                                                     u16* __restrict__ out, int R, int C,
                                                     float scale) {
  __shared__ float t[32][33];
  int c0 = blockIdx.x * 32, r0 = blockIdx.y * 32;
  int tx = threadIdx.x & 31, ty = threadIdx.x >> 5;
#pragma unroll
  for (int i = 0; i < 4; ++i)
    t[ty + i * 8][tx] = in[(r0 + ty + i * 8) * C + c0 + tx];
  __syncthreads();
#pragma unroll
  for (int i = 0; i < 4; ++i)
    out[(c0 + ty + i * 8) * R + r0 + tx] = f2bf(t[tx][ty + i * 8] * scale);
}

// ---------------- prep: bias concat [bq*QSCALE | bk | bv] + mask -> float bias ----
__global__ void k_prep(const float* __restrict__ bq, const float* __restrict__ bk,
                       const float* __restrict__ bv, float* __restrict__ bcat,
                       const int* __restrict__ m, float* __restrict__ mf) {
  int i = blockIdx.x * 256 + threadIdx.x;
  if (i < 3072) {
    float v = (i < 1024) ? bq[i] * QSCALE : (i < 2048 ? bk[i - 1024] : bv[i - 2048]);
    bcat[i] = v;
  }
  if (i < BATCH * S_LEN) mf[i] = m[i] ? -1e30f : 0.f;
}

// ---------------- bf16 V (inside qkvb, col offset 2048) -> vT [b][h][d][s] -------
__global__ void k_transpose_v(const u16* __restrict__ qkvb, u16* __restrict__ vT) {
  __shared__ u16 t[64][65];
  int s0 = blockIdx.x * 64;
  int bh = blockIdx.y;           // b*NHEAD + h
  int b = bh >> 4, h = bh & 15;
  int tx = threadIdx.x, ty = threadIdx.y;  // (64,4)
#pragma unroll
  for (int i = 0; i < 16; ++i) {
    int s = i * 4 + ty;
    t[s][tx] = qkvb[((s0 + s) * BATCH + b) * QKV_N + 2048 + h * HDIM + tx];
  }
  __syncthreads();
#pragma unroll
  for (int i = 0; i < 16; ++i) {
    int d = i * 4 + ty;
    vT[(bh * HDIM + d) * S_LEN + s0 + tx] = t[tx][d];
  }
}

// ---------------- 128x128 GEMM, BK=32, dbuf, swizzled, 2-phase, split-K ----------
template <int NS, bool RELU>
__global__ __launch_bounds__(256, 4) void k_gemm128(
    const u16* __restrict__ A, const u16* __restrict__ Bt,
    const float* __restrict__ bias, u16* __restrict__ C,
    u16* __restrict__ P1, u16* __restrict__ P2, u16* __restrict__ P3,
    int M, int N, int K, int nbx) {
  __shared__ u16 As[2][128 * 32];
  __shared__ u16 Bs[2][128 * 32];
  int tid = threadIdx.x;
  int lane = tid & 63;
  int lm = lane & 15, lg = lane >> 4;
  int w = tid >> 6;
  int wm = w >> 1, wn = w & 1;      // 2x2 waves; wave tile 64x64

  int cpx = gridDim.x >> 3;
  int nw = (blockIdx.x & 7) * cpx + (blockIdx.x >> 3);
  int nb = gridDim.x / NS;
  int slice = nw / nb;
  int t0 = nw - slice * nb;
  int m0 = (t0 / nbx) * 128, n0 = (t0 % nbx) * 128;
  int klen = K / NS, koff = slice * klen;

  f32x4 z = {0.f, 0.f, 0.f, 0.f};
  f32x4 acc[4][4];
#pragma unroll
  for (int mi = 0; mi < 4; ++mi)
#pragma unroll
    for (int ni = 0; ni < 4; ++ni) acc[mi][ni] = z;

  const u16* aSrc[2];
  const u16* bSrc[2];
  int dOff[2];
#pragma unroll
  for (int i = 0; i < 2; ++i) {
    int ci = i * 256 + tid;
    int row = ci >> 2, ch = ci & 3;
    int sc = 8 * (ch ^ ((row >> 1) & 3));
    aSrc[i] = A + (m0 + row) * K + koff + sc;
    bSrc[i] = Bt + (n0 + row) * K + koff + sc;
    dOff[i] = ci * 8;
  }

  auto stage = [&](int buf, int k0) {
#pragma unroll
    for (int i = 0; i < 2; ++i) {
      gload16(aSrc[i] + k0, &As[buf][0] + dOff[i]);
      gload16(bSrc[i] + k0, &Bs[buf][0] + dOff[i]);
    }
  };

  int swz = (lm >> 1) & 3;
  int nkt = klen >> 5;
  stage(0, 0);
  __syncthreads();
  for (int t = 0; t < nkt; ++t) {
    int cur = t & 1;
    if (t + 1 < nkt) stage(cur ^ 1, (t + 1) << 5);
    const u16* Ab = &As[cur][0];
    const u16* Bb = &Bs[cur][0];
    __builtin_amdgcn_s_setprio(1);
    short8 bf[4];
#pragma unroll
    for (int ni = 0; ni < 4; ++ni) {
      int row = wn * 64 + ni * 16 + lm;
      bf[ni] = *(const short8*)(Bb + row * 32 + 8 * (lg ^ swz));
    }
#pragma unroll
    for (int mi = 0; mi < 4; ++mi) {
      int row = wm * 64 + mi * 16 + lm;
      short8 af = *(const short8*)(Ab + row * 32 + 8 * (lg ^ swz));
#pragma unroll
      for (int ni = 0; ni < 4; ++ni)
        acc[mi][ni] = mfma16(af, bf[ni], acc[mi][ni]);
    }
    __builtin_amdgcn_s_setprio(0);
    __syncthreads();
  }

  u16* Cout = C;
  if (NS > 1) Cout = (slice == 0) ? C : (slice == 1 ? P1 : (slice == 2 ? P2 : P3));
#pragma unroll
  for (int ni = 0; ni < 4; ++ni) {
    int c = n0 + wn * 64 + ni * 16 + lm;
    float bc = (NS == 1) ? bias[c] : 0.f;
#pragma unroll
    for (int mi = 0; mi < 4; ++mi) {
#pragma unroll
      for (int j = 0; j < 4; ++j) {
        int r = m0 + wm * 64 + mi * 16 + lg * 4 + j;
        float x = acc[mi][ni][j] + bc;
        if (RELU) x = fmaxf(x, 0.f);
        Cout[r * N + c] = f2bf(x);
      }
    }
  }
}

// ---- reduce 4 bf16 partials + bias + resid (f32 or bf16), then layernorm --------
// RF32: residual is f32 (residf) else bf16 (residb).
// OUTF: write f32 outf, else write bf16 outb.
template <bool RF32, bool OUTF>
__global__ __launch_bounds__(256) void k_reduce_ln(
    const u16* __restrict__ P0, const u16* __restrict__ P1,
    const u16* __restrict__ P2, const u16* __restrict__ P3,
    const float* __restrict__ bias, const float* __restrict__ residf,
    const u16* __restrict__ residb, const float* __restrict__ gam,
    const float* __restrict__ bet, float* __restrict__ outf,
    u16* __restrict__ outb) {
  int r = blockIdx.x;
  int tid = threadIdx.x;
  int c4 = tid * 4;
  int idx = r * EMB + c4;
  u16x4 a0 = *(const u16x4*)(P0 + idx);
  u16x4 a1 = *(const u16x4*)(P1 + idx);
  u16x4 a2 = *(const u16x4*)(P2 + idx);
  u16x4 a3 = *(const u16x4*)(P3 + idx);
  float4 bi = *(const float4*)(bias + c4);
  float4 rs;
  if (RF32) {
    rs = *(const float4*)(residf + idx);
  } else {
    u16x4 rb = *(const u16x4*)(residb + idx);
    rs.x = bf2f(rb[0]); rs.y = bf2f(rb[1]); rs.z = bf2f(rb[2]); rs.w = bf2f(rb[3]);
  }
  float4 v;
  v.x = bf2f(a0[0]) + bf2f(a1[0]) + bf2f(a2[0]) + bf2f(a3[0]) + bi.x + rs.x;
  v.y = bf2f(a0[1]) + bf2f(a1[1]) + bf2f(a2[1]) + bf2f(a3[1]) + bi.y + rs.y;
  v.z = bf2f(a0[2]) + bf2f(a1[2]) + bf2f(a2[2]) + bf2f(a3[2]) + bi.z + rs.z;
  v.w = bf2f(a0[3]) + bf2f(a1[3]) + bf2f(a2[3]) + bf2f(a3[3]) + bi.w + rs.w;
  float s = v.x + v.y + v.z + v.w;
  float ss = v.x * v.x + v.y * v.y + v.z * v.z + v.w * v.w;
#pragma unroll
  for (int off = 1; off < 64; off <<= 1) {
    s += __shfl_xor(s, off);
    ss += __shfl_xor(ss, off);
  }
  __shared__ float red[2][4];
  int w = tid >> 6, lane = tid & 63;
  if (lane == 0) { red[0][w] = s; red[1][w] = ss; }
  __syncthreads();
  s = red[0][0] + red[0][1] + red[0][2] + red[0][3];
  ss = red[1][0] + red[1][1] + red[1][2] + red[1][3];
  float mean = s * (1.f / EMB);
  float var = ss * (1.f / EMB) - mean * mean;
  float inv = rsqrtf(var + 1e-5f);
  float4 g = *(const float4*)(gam + c4);
  float4 be = *(const float4*)(bet + c4);
  float4 o;
  o.x = (v.x - mean) * inv * g.x + be.x;
  o.y = (v.y - mean) * inv * g.y + be.y;
  o.z = (v.z - mean) * inv * g.z + be.z;
  o.w = (v.w - mean) * inv * g.w + be.w;
  if (OUTF) {
    *(float4*)(outf + idx) = o;
  } else {
    u16 ob[4] = {f2bf(o.x), f2bf(o.y), f2bf(o.z), f2bf(o.w)};
    *(u16x4*)(outb + idx) = *(u16x4*)ob;
  }
}

// ---------------- flash attention v8: v7 + conflict-free volatile b32 P-stores ---
__global__ __launch_bounds__(256) void k_attn(
    const u16* __restrict__ qkvb, const u16* __restrict__ vT,
    const float* __restrict__ maskf, u16* __restrict__ outb) {
  __shared__ u16 Kl[2][4096];
  __shared__ u16 Vl[2][4096];
  __shared__ u16 Pl[4][2048];            // per wave: 2 swizzled 16x64 P tiles
  int tid = threadIdx.x;
  int lane = tid & 63, w = tid >> 6;
  int lm = lane & 15, lg = lane >> 4;
  int L = blockIdx.x;                    // 0..511
  int bh = (L & 7) + 8 * (L >> 7);       // xcd-contiguous per (b,h); bijective
  int qi0 = ((L >> 3) & 15) * 128;
  int b = bh >> 4, h = bh & 15;

  short8 qf0[2], qf1[2];
#pragma unroll
  for (int qt = 0; qt < 2; ++qt) {
    int qs = qi0 + qt * 64 + w * 16 + lm;
    const u16* qp = qkvb + (qs * BATCH + b) * QKV_N + h * HDIM;
    qf0[qt] = *(const short8*)(qp + lg * 8);
    qf1[qt] = *(const short8*)(qp + 32 + lg * 8);
  }

  // staging: wave-uniform dests, per-lane pre-swizzled source (proven v4 pattern)
  int r0 = tid >> 3, c8 = tid & 7;
  int swz8 = 8 * (c8 ^ (r0 & 7));
  const u16* kA = qkvb + (r0 * BATCH + b) * QKV_N + 1024 + h * HDIM + swz8;
  const u16* kB = qkvb + ((r0 + 32) * BATCH + b) * QKV_N + 1024 + h * HDIM + swz8;
  const u16* vA = vT + (bh * HDIM + r0) * S_LEN + swz8;
  const u16* vB = vT + (bh * HDIM + r0 + 32) * S_LEN + swz8;
  const int KSTEP = 64 * BATCH * QKV_N;

  const float* mp = maskf + b * S_LEN;

  u16* Pw = Pl[w];
  int rd_swz = (lm & 7) << 3;
  const u16* prd0 = Pw + lm * 64 + ((lg * 8) ^ rd_swz);
  const u16* prd1 = Pw + lm * 64 + ((32 + lg * 8) ^ rd_swz);
  u16* pwr[4];
#pragma unroll
  for (int ni = 0; ni < 4; ++ni)
    pwr[ni] = Pw + lm * 64 + ((ni * 16 + lg * 4) ^ rd_swz);

  f32x4 z = {0.f, 0.f, 0.f, 0.f};
  f32x4 o[2][4] = {{z, z, z, z}, {z, z, z, z}};
  float lrow[2] = {0.f, 0.f};
  float4 mk[4], mknext[4];

  {
    u16* kd = Kl[0] + w * 512;
    u16* vd = Vl[0] + w * 512;
    gload16(kA, kd); gload16(kB, kd + 2048);
    gload16(vA, vd); gload16(vB, vd + 2048);
    kA += KSTEP; kB += KSTEP; vA += 64; vB += 64;
#pragma unroll
    for (int ni = 0; ni < 4; ++ni)
      mk[ni] = *(const float4*)(mp + ni * 16 + lg * 4);
  }
  __syncthreads();

  int cur = 0;
  for (int kt = 0; kt < S_LEN; kt += 64) {
    if (kt + 64 < S_LEN) {
      u16* kd = Kl[cur ^ 1] + w * 512;
      u16* vd = Vl[cur ^ 1] + w * 512;
      gload16(kA, kd); gload16(kB, kd + 2048);
      gload16(vA, vd); gload16(vB, vd + 2048);
      kA += KSTEP; kB += KSTEP; vA += 64; vB += 64;
#pragma unroll
      for (int ni = 0; ni < 4; ++ni)
        mknext[ni] = *(const float4*)(mp + kt + 64 + ni * 16 + lg * 4);
    }
    const u16* Kc = Kl[cur];
    const u16* Vc = Vl[cur];
#pragma unroll
    for (int ni = 0; ni < 4; ++ni) {
      const u16* kl = Kc + (ni * 16 + lm) * 64;
      short8 k0 = *(const short8*)(kl + ((lg * 8) ^ rd_swz));
      short8 k1 = *(const short8*)(kl + ((32 + lg * 8) ^ rd_swz));
      float4 mb = mk[ni];
#pragma unroll
      for (int qt = 0; qt < 2; ++qt) {
        // swapped: rows = keys (ni*16+lg*4+j), col = query lm; exp2 domain
        f32x4 t = mfma16(k0, qf0[qt], z);
        f32x4 sv = mfma16(k1, qf1[qt], t);
        float p0 = __builtin_amdgcn_exp2f(sv[0] + mb.x);
        float p1 = __builtin_amdgcn_exp2f(sv[1] + mb.y);
        float p2 = __builtin_amdgcn_exp2f(sv[2] + mb.z);
        float p3 = __builtin_amdgcn_exp2f(sv[3] + mb.w);
        lrow[qt] += (p0 + p1) + (p2 + p3);
        // two volatile b32 stores: no b64 merge -> conflict-free P write
        volatile u32* pw = (volatile u32*)(pwr[ni] + qt * 1024);
        pw[0] = cvtpk(p0, p1);
        pw[1] = cvtpk(p2, p3);
      }
    }
    short8 pa0[2], pa1[2];
#pragma unroll
    for (int qt = 0; qt < 2; ++qt) {
      pa0[qt] = *(const short8*)(prd0 + qt * 1024);
      pa1[qt] = *(const short8*)(prd1 + qt * 1024);
    }
#pragma unroll
    for (int ni = 0; ni < 4; ++ni) {
      const u16* vl = Vc + (ni * 16 + lm) * 64;
      short8 v0 = *(const short8*)(vl + ((lg * 8) ^ rd_swz));
      short8 v1 = *(const short8*)(vl + ((32 + lg * 8) ^ rd_swz));
#pragma unroll
      for (int qt = 0; qt < 2; ++qt) {
        o[qt][ni] = mfma16(pa0[qt], v0, o[qt][ni]);
        o[qt][ni] = mfma16(pa1[qt], v1, o[qt][ni]);
      }
    }
#pragma unroll
    for (int ni = 0; ni < 4; ++ni) mk[ni] = mknext[ni];
    __syncthreads();
    cur ^= 1;
  }

#pragma unroll
  for (int qt = 0; qt < 2; ++qt) {
    float l = lrow[qt];
    l += __shfl_xor(l, 16);
    l += __shfl_xor(l, 32);
    float inv = 1.f / l;
    float invj[4];
#pragma unroll
    for (int j = 0; j < 4; ++j) invj[j] = __shfl(inv, lg * 4 + j);
#pragma unroll
    for (int ni = 0; ni < 4; ++ni) {
      int c = h * HDIM + ni * 16 + lm;
#pragma unroll
      for (int j = 0; j < 4; ++j) {
        int srow = qi0 + qt * 64 + w * 16 + lg * 4 + j;
        outb[(srow * BATCH + b) * EMB + c] = f2bf(o[qt][ni][j] * invj[j]);
      }
    }
  }
}

extern "C" void kernel_launch(void* const* d_in, const int* in_sizes, int n_in,
                              void* d_out, int out_size, void* d_ws, size_t ws_size,
                              hipStream_t stream) {
  (void)in_sizes; (void)n_in; (void)out_size; (void)ws_size;
  const float* x = (const float*)d_in[0];
  const int* mask = (const int*)d_in[1];
  const float* Wq = (const float*)d_in[2];
  const float* bq = (const float*)d_in[3];
  const float* Wk = (const float*)d_in[4];
  const float* bk = (const float*)d_in[5];
  const float* Wv = (const float*)d_in[6];
  const float* bv = (const float*)d_in[7];
  const float* Wo = (const float*)d_in[8];
  const float* bo = (const float*)d_in[9];
  const float* g1 = (const float*)d_in[10];
  const float* be1 = (const float*)d_in[11];
  const float* W1 = (const float*)d_in[12];
  const float* b1 = (const float*)d_in[13];
  const float* W2 = (const float*)d_in[14];
  const float* b2 = (const float*)d_in[15];
  const float* g2 = (const float*)d_in[16];
  const float* be2 = (const float*)d_in[17];
  float* out = (float*)d_out;

  // workspace layout (109.1 MB):
  // [0, 8.4M)        xb -> vT -> PP0
  // [8.4M, 33.5M)    weights: WqkvT | WoT | W1T | W2T
  // [33.5M, 58.7M)   qkvb --\  f1b spans [33.5M, 67.1M)
  // [58.7M, 67.1M)   ao ----/
  // [67.1M, +32K)    bcat (12K) + maskf (16K)
  // [67.1M+64K, ..)  PP1 (8.4M, ends ~75.6M)
  // [83.9M, 92.3M)   hb (bf16 LN1 out; FFN1 A; FFN2 resid) -- NOT aliased by PP*
  // [92.3M, 100.7M)  PP2
  // [100.7M, 109.1M) PP3
  char* p = (char*)d_ws;
  u16* xb = (u16*)(p);
  u16* WqkvT = (u16*)(p + 8388608);
  u16* WoT = WqkvT + 3 * 1024 * 1024;
  u16* W1T = WoT + 1024 * 1024;
  u16* W2T = W1T + 1024 * 4096;
  u16* qkvb = (u16*)(p + 33554432);
  u16* ao = (u16*)(p + 58720256);
  float* bcat = (float*)(p + 67108864);
  float* maskf = (float*)(p + 67108864 + 16384);
  u16* PP1 = (u16*)(p + 67108864 + 65536);
  u16* hb = (u16*)(p + 83886080);
  u16* vT = xb;
  u16* f1b = qkvb;
  u16* PP0 = xb;
  u16* PP2 = (u16*)(p + 92274688);
  u16* PP3 = (u16*)(p + 100663296);

  // conversions / transposes / prep
  k_cvt_bf16<<<NTOK * EMB / 2048, 256, 0, stream>>>(x, xb, NTOK * EMB);
  k_transpose_w<<<dim3(32, 32), 256, 0, stream>>>(Wq, WqkvT, 1024, 1024, QSCALE);
  k_transpose_w<<<dim3(32, 32), 256, 0, stream>>>(Wk, WqkvT + 1024 * 1024, 1024, 1024, 1.f);
  k_transpose_w<<<dim3(32, 32), 256, 0, stream>>>(Wv, WqkvT + 2 * 1024 * 1024, 1024, 1024, 1.f);
  k_transpose_w<<<dim3(32, 32), 256, 0, stream>>>(Wo, WoT, 1024, 1024, 1.f);
  k_transpose_w<<<dim3(128, 32), 256, 0, stream>>>(W1, W1T, 1024, 4096, 1.f);
  k_transpose_w<<<dim3(32, 128), 256, 0, stream>>>(W2, W2T, 4096, 1024, 1.f);
  k_prep<<<16, 256, 0, stream>>>(bq, bk, bv, bcat, mask, maskf);

  // fused QKV projection: grid 768 (3 blocks/CU)
  k_gemm128<1, false><<<(NTOK / 128) * (QKV_N / 128), 256, 0, stream>>>(
      xb, WqkvT, bcat, qkvb, nullptr, nullptr, nullptr, NTOK, QKV_N, EMB, QKV_N / 128);

  // V transpose, attention (512 blocks, 128 queries each)
  k_transpose_v<<<dim3(S_LEN / 64, BATCH * NHEAD), dim3(64, 4), 0, stream>>>(qkvb, vT);
  k_attn<<<512, 256, 0, stream>>>(qkvb, vT, maskf, ao);

  // O-proj split-K=4, then fused reduce + f32 resid(x) + LN1 -> hb (bf16 only)
  k_gemm128<4, false><<<(NTOK / 128) * (EMB / 128) * 4, 256, 0, stream>>>(
      ao, WoT, nullptr, PP0, PP1, PP2, PP3, NTOK, EMB, EMB, EMB / 128);
  k_reduce_ln<true, false><<<NTOK, 256, 0, stream>>>(
      PP0, PP1, PP2, PP3, bo, x, nullptr, g1, be1, nullptr, hb);

  // FFN1 (grid 1024, relu, bf16 out)
  k_gemm128<1, true><<<(NTOK / 128) * (FFN_DIM / 128), 256, 0, stream>>>(
      hb, W1T, b1, f1b, nullptr, nullptr, nullptr, NTOK, FFN_DIM, EMB, FFN_DIM / 128);

  // FFN2 split-K=4, then fused reduce + bf16 resid(hb) + LN2 -> out (f32)
  k_gemm128<4, false><<<(NTOK / 128) * (EMB / 128) * 4, 256, 0, stream>>>(
      f1b, W2T, nullptr, PP0, PP1, PP2, PP3, NTOK, EMB, FFN_DIM, EMB / 128);
  k_reduce_ln<false, true><<<NTOK, 256, 0, stream>>>(
      PP0, PP1, PP2, PP3, b2, nullptr, hb, g2, be2, out, nullptr);
}

// Round 13
// 244.957 us; speedup vs baseline: 1.0620x; 1.0620x over previous
//
#include <hip/hip_runtime.h>
#include <hip/hip_bf16.h>

using u16 = unsigned short;
using u32 = unsigned int;

constexpr int S_LEN = 2048, BATCH = 2, EMB = 1024, NHEAD = 16, HDIM = 64, FFN_DIM = 4096;
constexpr int NTOK = S_LEN * BATCH;
constexpr int QKV_N = 3 * EMB;  // 3072
// q pre-scale: 1/sqrt(64) * log2(e)  (softmax computed in exp2 domain)
#define QSCALE 0.18033688011112042f

typedef __attribute__((ext_vector_type(4))) float f32x4;
typedef __attribute__((ext_vector_type(8))) short short8;
typedef __attribute__((ext_vector_type(8))) __bf16 bf16x8;
typedef __attribute__((ext_vector_type(8))) u16 ushort8;
typedef __attribute__((ext_vector_type(4))) u16 u16x4;
typedef __attribute__((ext_vector_type(2))) u32 u32x2;

typedef const __attribute__((address_space(1))) u16 gu16;
typedef __attribute__((address_space(3))) u16 lu16;

__device__ __forceinline__ u16 f2bf(float f) {
  u32 u = __builtin_bit_cast(u32, f);
  u32 r = u + 0x7fffu + ((u >> 16) & 1u);
  return (u16)(r >> 16);
}
__device__ __forceinline__ float bf2f(u16 u) {
  return __builtin_bit_cast(float, (u32)u << 16);
}

__device__ __forceinline__ f32x4 mfma16(short8 a, short8 b, f32x4 c) {
  return __builtin_amdgcn_mfma_f32_16x16x32_bf16(
      __builtin_bit_cast(bf16x8, a), __builtin_bit_cast(bf16x8, b), c, 0, 0, 0);
}

__device__ __forceinline__ void gload16(const u16* g, u16* l) {
  __builtin_amdgcn_global_load_lds((gu16*)g, (lu16*)l, 16, 0, 0);
}

__device__ __forceinline__ u32 cvtpk(float lo, float hi) {
  u32 r;
  asm("v_cvt_pk_bf16_f32 %0, %1, %2" : "=v"(r) : "v"(lo), "v"(hi));
  return r;
}

// ---------------- fp32 -> bf16 elementwise ----------------
__global__ __launch_bounds__(256) void k_cvt_bf16(const float* __restrict__ in,
                                                  u16* __restrict__ out, int n) {
  int i = (blockIdx.x * 256 + threadIdx.x) * 8;
  if (i >= n) return;
  float4 a = *(const float4*)(in + i);
  float4 b = *(const float4*)(in + i + 4);
  ushort8 o;
  o[0] = f2bf(a.x); o[1] = f2bf(a.y); o[2] = f2bf(a.z); o[3] = f2bf(a.w);
  o[4] = f2bf(b.x); o[5] = f2bf(b.y); o[6] = f2bf(b.z); o[7] = f2bf(b.w);
  *(ushort8*)(out + i) = o;
}

// ---------------- fp32 [R][C] -> bf16 [C][R] (weight transpose, optional scale) ----
__global__ __launch_bounds__(256) void k_transpose_w(const float* __restrict__ in,
                                                     u16* __restrict__ out, int R, int C,
                                                     float scale) {
  __shared__ float t[32][33];
  int c0 = blockIdx.x * 32, r0 = blockIdx.y * 32;
  int tx = threadIdx.x & 31, ty = threadIdx.x >> 5;
#pragma unroll
  for (int i = 0; i < 4; ++i)
    t[ty + i * 8][tx] = in[(r0 + ty + i * 8) * C + c0 + tx];
  __syncthreads();
#pragma unroll
  for (int i = 0; i < 4; ++i)
    out[(c0 + ty + i * 8) * R + r0 + tx] = f2bf(t[tx][ty + i * 8] * scale);
}

// ---------------- prep: bias concat [bq*QSCALE | bk | bv] + mask -> float bias ----
__global__ void k_prep(const float* __restrict__ bq, const float* __restrict__ bk,
                       const float* __restrict__ bv, float* __restrict__ bcat,
                       const int* __restrict__ m, float* __restrict__ mf) {
  int i = blockIdx.x * 256 + threadIdx.x;
  if (i < 3072) {
    float v = (i < 1024) ? bq[i] * QSCALE : (i < 2048 ? bk[i - 1024] : bv[i - 2048]);
    bcat[i] = v;
  }
  if (i < BATCH * S_LEN) mf[i] = m[i] ? -1e30f : 0.f;
}

// ---------------- bf16 V (inside qkvb, col offset 2048) -> vT [b][h][d][s] -------
__global__ void k_transpose_v(const u16* __restrict__ qkvb, u16* __restrict__ vT) {
  __shared__ u16 t[64][65];
  int s0 = blockIdx.x * 64;
  int bh = blockIdx.y;           // b*NHEAD + h
  int b = bh >> 4, h = bh & 15;
  int tx = threadIdx.x, ty = threadIdx.y;  // (64,4)
#pragma unroll
  for (int i = 0; i < 16; ++i) {
    int s = i * 4 + ty;
    t[s][tx] = qkvb[((s0 + s) * BATCH + b) * QKV_N + 2048 + h * HDIM + tx];
  }
  __syncthreads();
#pragma unroll
  for (int i = 0; i < 16; ++i) {
    int d = i * 4 + ty;
    vT[(bh * HDIM + d) * S_LEN + s0 + tx] = t[tx][d];
  }
}

// ---------------- 128x128 GEMM, BK=32, dbuf, swizzled, 2-phase, split-K ----------
template <int NS, bool RELU>
__global__ __launch_bounds__(256, 4) void k_gemm128(
    const u16* __restrict__ A, const u16* __restrict__ Bt,
    const float* __restrict__ bias, u16* __restrict__ C,
    u16* __restrict__ P1, u16* __restrict__ P2, u16* __restrict__ P3,
    int M, int N, int K, int nbx) {
  __shared__ u16 As[2][128 * 32];
  __shared__ u16 Bs[2][128 * 32];
  int tid = threadIdx.x;
  int lane = tid & 63;
  int lm = lane & 15, lg = lane >> 4;
  int w = tid >> 6;
  int wm = w >> 1, wn = w & 1;      // 2x2 waves; wave tile 64x64

  int cpx = gridDim.x >> 3;
  int nw = (blockIdx.x & 7) * cpx + (blockIdx.x >> 3);
  int nb = gridDim.x / NS;
  int slice = nw / nb;
  int t0 = nw - slice * nb;
  int m0 = (t0 / nbx) * 128, n0 = (t0 % nbx) * 128;
  int klen = K / NS, koff = slice * klen;

  f32x4 z = {0.f, 0.f, 0.f, 0.f};
  f32x4 acc[4][4];
#pragma unroll
  for (int mi = 0; mi < 4; ++mi)
#pragma unroll
    for (int ni = 0; ni < 4; ++ni) acc[mi][ni] = z;

  const u16* aSrc[2];
  const u16* bSrc[2];
  int dOff[2];
#pragma unroll
  for (int i = 0; i < 2; ++i) {
    int ci = i * 256 + tid;
    int row = ci >> 2, ch = ci & 3;
    int sc = 8 * (ch ^ ((row >> 1) & 3));
    aSrc[i] = A + (m0 + row) * K + koff + sc;
    bSrc[i] = Bt + (n0 + row) * K + koff + sc;
    dOff[i] = ci * 8;
  }

  auto stage = [&](int buf, int k0) {
#pragma unroll
    for (int i = 0; i < 2; ++i) {
      gload16(aSrc[i] + k0, &As[buf][0] + dOff[i]);
      gload16(bSrc[i] + k0, &Bs[buf][0] + dOff[i]);
    }
  };

  int swz = (lm >> 1) & 3;
  int nkt = klen >> 5;
  stage(0, 0);
  __syncthreads();
  for (int t = 0; t < nkt; ++t) {
    int cur = t & 1;
    if (t + 1 < nkt) stage(cur ^ 1, (t + 1) << 5);
    const u16* Ab = &As[cur][0];
    const u16* Bb = &Bs[cur][0];
    __builtin_amdgcn_s_setprio(1);
    short8 bf[4];
#pragma unroll
    for (int ni = 0; ni < 4; ++ni) {
      int row = wn * 64 + ni * 16 + lm;
      bf[ni] = *(const short8*)(Bb + row * 32 + 8 * (lg ^ swz));
    }
#pragma unroll
    for (int mi = 0; mi < 4; ++mi) {
      int row = wm * 64 + mi * 16 + lm;
      short8 af = *(const short8*)(Ab + row * 32 + 8 * (lg ^ swz));
#pragma unroll
      for (int ni = 0; ni < 4; ++ni)
        acc[mi][ni] = mfma16(af, bf[ni], acc[mi][ni]);
    }
    __builtin_amdgcn_s_setprio(0);
    __syncthreads();
  }

  u16* Cout = C;
  if (NS > 1) Cout = (slice == 0) ? C : (slice == 1 ? P1 : (slice == 2 ? P2 : P3));
#pragma unroll
  for (int ni = 0; ni < 4; ++ni) {
    int c = n0 + wn * 64 + ni * 16 + lm;
    float bc = (NS == 1) ? bias[c] : 0.f;
#pragma unroll
    for (int mi = 0; mi < 4; ++mi) {
#pragma unroll
      for (int j = 0; j < 4; ++j) {
        int r = m0 + wm * 64 + mi * 16 + lg * 4 + j;
        float x = acc[mi][ni][j] + bc;
        if (RELU) x = fmaxf(x, 0.f);
        Cout[r * N + c] = f2bf(x);
      }
    }
  }
}

// ---- reduce 4 bf16 partials + bias + resid (f32 or bf16), then layernorm --------
template <bool RF32, bool OUTF>
__global__ __launch_bounds__(256) void k_reduce_ln(
    const u16* __restrict__ P0, const u16* __restrict__ P1,
    const u16* __restrict__ P2, const u16* __restrict__ P3,
    const float* __restrict__ bias, const float* __restrict__ residf,
    const u16* __restrict__ residb, const float* __restrict__ gam,
    const float* __restrict__ bet, float* __restrict__ outf,
    u16* __restrict__ outb) {
  int r = blockIdx.x;
  int tid = threadIdx.x;
  int c4 = tid * 4;
  int idx = r * EMB + c4;
  u16x4 a0 = *(const u16x4*)(P0 + idx);
  u16x4 a1 = *(const u16x4*)(P1 + idx);
  u16x4 a2 = *(const u16x4*)(P2 + idx);
  u16x4 a3 = *(const u16x4*)(P3 + idx);
  float4 bi = *(const float4*)(bias + c4);
  float4 rs;
  if (RF32) {
    rs = *(const float4*)(residf + idx);
  } else {
    u16x4 rb = *(const u16x4*)(residb + idx);
    rs.x = bf2f(rb[0]); rs.y = bf2f(rb[1]); rs.z = bf2f(rb[2]); rs.w = bf2f(rb[3]);
  }
  float4 v;
  v.x = bf2f(a0[0]) + bf2f(a1[0]) + bf2f(a2[0]) + bf2f(a3[0]) + bi.x + rs.x;
  v.y = bf2f(a0[1]) + bf2f(a1[1]) + bf2f(a2[1]) + bf2f(a3[1]) + bi.y + rs.y;
  v.z = bf2f(a0[2]) + bf2f(a1[2]) + bf2f(a2[2]) + bf2f(a3[2]) + bi.z + rs.z;
  v.w = bf2f(a0[3]) + bf2f(a1[3]) + bf2f(a2[3]) + bf2f(a3[3]) + bi.w + rs.w;
  float s = v.x + v.y + v.z + v.w;
  float ss = v.x * v.x + v.y * v.y + v.z * v.z + v.w * v.w;
#pragma unroll
  for (int off = 1; off < 64; off <<= 1) {
    s += __shfl_xor(s, off);
    ss += __shfl_xor(ss, off);
  }
  __shared__ float red[2][4];
  int w = tid >> 6, lane = tid & 63;
  if (lane == 0) { red[0][w] = s; red[1][w] = ss; }
  __syncthreads();
  s = red[0][0] + red[0][1] + red[0][2] + red[0][3];
  ss = red[1][0] + red[1][1] + red[1][2] + red[1][3];
  float mean = s * (1.f / EMB);
  float var = ss * (1.f / EMB) - mean * mean;
  float inv = rsqrtf(var + 1e-5f);
  float4 g = *(const float4*)(gam + c4);
  float4 be = *(const float4*)(bet + c4);
  float4 o;
  o.x = (v.x - mean) * inv * g.x + be.x;
  o.y = (v.y - mean) * inv * g.y + be.y;
  o.z = (v.z - mean) * inv * g.z + be.z;
  o.w = (v.w - mean) * inv * g.w + be.w;
  if (OUTF) {
    *(float4*)(outf + idx) = o;
  } else {
    u16 ob[4] = {f2bf(o.x), f2bf(o.y), f2bf(o.z), f2bf(o.w)};
    *(u16x4*)(outb + idx) = *(u16x4*)ob;
  }
}

// ---------------- flash attention v7 (proven): 2 query-tiles, b64 P store -------
__global__ __launch_bounds__(256) void k_attn(
    const u16* __restrict__ qkvb, const u16* __restrict__ vT,
    const float* __restrict__ maskf, u16* __restrict__ outb) {
  __shared__ u16 Kl[2][4096];
  __shared__ u16 Vl[2][4096];
  __shared__ u16 Pl[4][2048];            // per wave: 2 swizzled 16x64 P tiles
  int tid = threadIdx.x;
  int lane = tid & 63, w = tid >> 6;
  int lm = lane & 15, lg = lane >> 4;
  int L = blockIdx.x;                    // 0..511
  int bh = (L & 7) + 8 * (L >> 7);       // xcd-contiguous per (b,h); bijective
  int qi0 = ((L >> 3) & 15) * 128;
  int b = bh >> 4, h = bh & 15;

  short8 qf0[2], qf1[2];
#pragma unroll
  for (int qt = 0; qt < 2; ++qt) {
    int qs = qi0 + qt * 64 + w * 16 + lm;
    const u16* qp = qkvb + (qs * BATCH + b) * QKV_N + h * HDIM;
    qf0[qt] = *(const short8*)(qp + lg * 8);
    qf1[qt] = *(const short8*)(qp + 32 + lg * 8);
  }

  // staging: wave-uniform dests, per-lane pre-swizzled source (proven v4 pattern)
  int r0 = tid >> 3, c8 = tid & 7;
  int swz8 = 8 * (c8 ^ (r0 & 7));
  const u16* kA = qkvb + (r0 * BATCH + b) * QKV_N + 1024 + h * HDIM + swz8;
  const u16* kB = qkvb + ((r0 + 32) * BATCH + b) * QKV_N + 1024 + h * HDIM + swz8;
  const u16* vA = vT + (bh * HDIM + r0) * S_LEN + swz8;
  const u16* vB = vT + (bh * HDIM + r0 + 32) * S_LEN + swz8;
  const int KSTEP = 64 * BATCH * QKV_N;

  const float* mp = maskf + b * S_LEN;

  u16* Pw = Pl[w];
  int rd_swz = (lm & 7) << 3;
  const u16* prd0 = Pw + lm * 64 + ((lg * 8) ^ rd_swz);
  const u16* prd1 = Pw + lm * 64 + ((32 + lg * 8) ^ rd_swz);
  u16* pwr[4];
#pragma unroll
  for (int ni = 0; ni < 4; ++ni)
    pwr[ni] = Pw + lm * 64 + ((ni * 16 + lg * 4) ^ rd_swz);

  f32x4 z = {0.f, 0.f, 0.f, 0.f};
  f32x4 o[2][4] = {{z, z, z, z}, {z, z, z, z}};
  float lrow[2] = {0.f, 0.f};
  float4 mk[4], mknext[4];

  {
    u16* kd = Kl[0] + w * 512;
    u16* vd = Vl[0] + w * 512;
    gload16(kA, kd); gload16(kB, kd + 2048);
    gload16(vA, vd); gload16(vB, vd + 2048);
    kA += KSTEP; kB += KSTEP; vA += 64; vB += 64;
#pragma unroll
    for (int ni = 0; ni < 4; ++ni)
      mk[ni] = *(const float4*)(mp + ni * 16 + lg * 4);
  }
  __syncthreads();

  int cur = 0;
  for (int kt = 0; kt < S_LEN; kt += 64) {
    if (kt + 64 < S_LEN) {
      u16* kd = Kl[cur ^ 1] + w * 512;
      u16* vd = Vl[cur ^ 1] + w * 512;
      gload16(kA, kd); gload16(kB, kd + 2048);
      gload16(vA, vd); gload16(vB, vd + 2048);
      kA += KSTEP; kB += KSTEP; vA += 64; vB += 64;
#pragma unroll
      for (int ni = 0; ni < 4; ++ni)
        mknext[ni] = *(const float4*)(mp + kt + 64 + ni * 16 + lg * 4);
    }
    const u16* Kc = Kl[cur];
    const u16* Vc = Vl[cur];
#pragma unroll
    for (int ni = 0; ni < 4; ++ni) {
      const u16* kl = Kc + (ni * 16 + lm) * 64;
      short8 k0 = *(const short8*)(kl + ((lg * 8) ^ rd_swz));
      short8 k1 = *(const short8*)(kl + ((32 + lg * 8) ^ rd_swz));
      float4 mb = mk[ni];
#pragma unroll
      for (int qt = 0; qt < 2; ++qt) {
        // swapped: rows = keys (ni*16+lg*4+j), col = query lm; exp2 domain
        f32x4 t = mfma16(k0, qf0[qt], z);
        f32x4 sv = mfma16(k1, qf1[qt], t);
        float p0 = __builtin_amdgcn_exp2f(sv[0] + mb.x);
        float p1 = __builtin_amdgcn_exp2f(sv[1] + mb.y);
        float p2 = __builtin_amdgcn_exp2f(sv[2] + mb.z);
        float p3 = __builtin_amdgcn_exp2f(sv[3] + mb.w);
        lrow[qt] += (p0 + p1) + (p2 + p3);
        u32x2 pk;
        pk[0] = cvtpk(p0, p1);
        pk[1] = cvtpk(p2, p3);
        *(u32x2*)(pwr[ni] + qt * 1024) = pk;   // ds_write_b64: 4 keys packed
      }
    }
    short8 pa0[2], pa1[2];
#pragma unroll
    for (int qt = 0; qt < 2; ++qt) {
      pa0[qt] = *(const short8*)(prd0 + qt * 1024);
      pa1[qt] = *(const short8*)(prd1 + qt * 1024);
    }
#pragma unroll
    for (int ni = 0; ni < 4; ++ni) {
      const u16* vl = Vc + (ni * 16 + lm) * 64;
      short8 v0 = *(const short8*)(vl + ((lg * 8) ^ rd_swz));
      short8 v1 = *(const short8*)(vl + ((32 + lg * 8) ^ rd_swz));
#pragma unroll
      for (int qt = 0; qt < 2; ++qt) {
        o[qt][ni] = mfma16(pa0[qt], v0, o[qt][ni]);
        o[qt][ni] = mfma16(pa1[qt], v1, o[qt][ni]);
      }
    }
#pragma unroll
    for (int ni = 0; ni < 4; ++ni) mk[ni] = mknext[ni];
    __syncthreads();
    cur ^= 1;
  }

#pragma unroll
  for (int qt = 0; qt < 2; ++qt) {
    float l = lrow[qt];
    l += __shfl_xor(l, 16);
    l += __shfl_xor(l, 32);
    float inv = 1.f / l;
    float invj[4];
#pragma unroll
    for (int j = 0; j < 4; ++j) invj[j] = __shfl(inv, lg * 4 + j);
#pragma unroll
    for (int ni = 0; ni < 4; ++ni) {
      int c = h * HDIM + ni * 16 + lm;
#pragma unroll
      for (int j = 0; j < 4; ++j) {
        int srow = qi0 + qt * 64 + w * 16 + lg * 4 + j;
        outb[(srow * BATCH + b) * EMB + c] = f2bf(o[qt][ni][j] * invj[j]);
      }
    }
  }
}

extern "C" void kernel_launch(void* const* d_in, const int* in_sizes, int n_in,
                              void* d_out, int out_size, void* d_ws, size_t ws_size,
                              hipStream_t stream) {
  (void)in_sizes; (void)n_in; (void)out_size; (void)ws_size;
  const float* x = (const float*)d_in[0];
  const int* mask = (const int*)d_in[1];
  const float* Wq = (const float*)d_in[2];
  const float* bq = (const float*)d_in[3];
  const float* Wk = (const float*)d_in[4];
  const float* bk = (const float*)d_in[5];
  const float* Wv = (const float*)d_in[6];
  const float* bv = (const float*)d_in[7];
  const float* Wo = (const float*)d_in[8];
  const float* bo = (const float*)d_in[9];
  const float* g1 = (const float*)d_in[10];
  const float* be1 = (const float*)d_in[11];
  const float* W1 = (const float*)d_in[12];
  const float* b1 = (const float*)d_in[13];
  const float* W2 = (const float*)d_in[14];
  const float* b2 = (const float*)d_in[15];
  const float* g2 = (const float*)d_in[16];
  const float* be2 = (const float*)d_in[17];
  float* out = (float*)d_out;

  // workspace layout (109.1 MB):
  // [0, 8.4M)        xb -> vT -> PP0
  // [8.4M, 33.5M)    weights: WqkvT | WoT | W1T | W2T
  // [33.5M, 58.7M)   qkvb --\  f1b spans [33.5M, 67.1M)
  // [58.7M, 67.1M)   ao ----/
  // [67.1M, +32K)    bcat (12K) + maskf (16K)
  // [67.1M+64K, ..)  PP1 (8.4M)
  // [83.9M, 92.3M)   hb (bf16 LN1 out; FFN1 A; FFN2 resid)
  // [92.3M, 100.7M)  PP2
  // [100.7M, 109.1M) PP3
  char* p = (char*)d_ws;
  u16* xb = (u16*)(p);
  u16* WqkvT = (u16*)(p + 8388608);
  u16* WoT = WqkvT + 3 * 1024 * 1024;
  u16* W1T = WoT + 1024 * 1024;
  u16* W2T = W1T + 1024 * 4096;
  u16* qkvb = (u16*)(p + 33554432);
  u16* ao = (u16*)(p + 58720256);
  float* bcat = (float*)(p + 67108864);
  float* maskf = (float*)(p + 67108864 + 16384);
  u16* PP1 = (u16*)(p + 67108864 + 65536);
  u16* hb = (u16*)(p + 83886080);
  u16* vT = xb;
  u16* f1b = qkvb;
  u16* PP0 = xb;
  u16* PP2 = (u16*)(p + 92274688);
  u16* PP3 = (u16*)(p + 100663296);

  // conversions / transposes / prep
  k_cvt_bf16<<<NTOK * EMB / 2048, 256, 0, stream>>>(x, xb, NTOK * EMB);
  k_transpose_w<<<dim3(32, 32), 256, 0, stream>>>(Wq, WqkvT, 1024, 1024, QSCALE);
  k_transpose_w<<<dim3(32, 32), 256, 0, stream>>>(Wk, WqkvT + 1024 * 1024, 1024, 1024, 1.f);
  k_transpose_w<<<dim3(32, 32), 256, 0, stream>>>(Wv, WqkvT + 2 * 1024 * 1024, 1024, 1024, 1.f);
  k_transpose_w<<<dim3(32, 32), 256, 0, stream>>>(Wo, WoT, 1024, 1024, 1.f);
  k_transpose_w<<<dim3(128, 32), 256, 0, stream>>>(W1, W1T, 1024, 4096, 1.f);
  k_transpose_w<<<dim3(32, 128), 256, 0, stream>>>(W2, W2T, 4096, 1024, 1.f);
  k_prep<<<16, 256, 0, stream>>>(bq, bk, bv, bcat, mask, maskf);

  // fused QKV projection: grid 768 (3 blocks/CU)
  k_gemm128<1, false><<<(NTOK / 128) * (QKV_N / 128), 256, 0, stream>>>(
      xb, WqkvT, bcat, qkvb, nullptr, nullptr, nullptr, NTOK, QKV_N, EMB, QKV_N / 128);

  // V transpose, attention (512 blocks, 128 queries each)
  k_transpose_v<<<dim3(S_LEN / 64, BATCH * NHEAD), dim3(64, 4), 0, stream>>>(qkvb, vT);
  k_attn<<<512, 256, 0, stream>>>(qkvb, vT, maskf, ao);

  // O-proj split-K=4, then fused reduce + f32 resid(x) + LN1 -> hb (bf16 only)
  k_gemm128<4, false><<<(NTOK / 128) * (EMB / 128) * 4, 256, 0, stream>>>(
      ao, WoT, nullptr, PP0, PP1, PP2, PP3, NTOK, EMB, EMB, EMB / 128);
  k_reduce_ln<true, false><<<NTOK, 256, 0, stream>>>(
      PP0, PP1, PP2, PP3, bo, x, nullptr, g1, be1, nullptr, hb);

  // FFN1 (grid 1024, relu, bf16 out)
  k_gemm128<1, true><<<(NTOK / 128) * (FFN_DIM / 128), 256, 0, stream>>>(
      hb, W1T, b1, f1b, nullptr, nullptr, nullptr, NTOK, FFN_DIM, EMB, FFN_DIM / 128);

  // FFN2 split-K=4, then fused reduce + bf16 resid(hb) + LN2 -> out (f32)
  k_gemm128<4, false><<<(NTOK / 128) * (EMB / 128) * 4, 256, 0, stream>>>(
      f1b, W2T, nullptr, PP0, PP1, PP2, PP3, NTOK, EMB, FFN_DIM, EMB / 128);
  k_reduce_ln<false, true><<<NTOK, 256, 0, stream>>>(
      PP0, PP1, PP2, PP3, b2, nullptr, hb, g2, be2, out, nullptr);
}

// Round 15
// 239.762 us; speedup vs baseline: 1.0850x; 1.0217x over previous
//
#include <hip/hip_runtime.h>
#include <hip/hip_bf16.h>

using u16 = unsigned short;
using u32 = unsigned int;

constexpr int S_LEN = 2048, BATCH = 2, EMB = 1024, NHEAD = 16, HDIM = 64, FFN_DIM = 4096;
constexpr int NTOK = S_LEN * BATCH;
constexpr int QKV_N = 3 * EMB;  // 3072
// q pre-scale: 1/sqrt(64) * log2(e)  (softmax computed in exp2 domain)
#define QSCALE 0.18033688011112042f

typedef __attribute__((ext_vector_type(4))) float f32x4;
typedef __attribute__((ext_vector_type(8))) short short8;
typedef __attribute__((ext_vector_type(8))) __bf16 bf16x8;
typedef __attribute__((ext_vector_type(8))) u16 ushort8;
typedef __attribute__((ext_vector_type(4))) u16 u16x4;
typedef __attribute__((ext_vector_type(2))) u32 u32x2;

typedef const __attribute__((address_space(1))) u16 gu16;
typedef __attribute__((address_space(3))) u16 lu16;

__device__ __forceinline__ u16 f2bf(float f) {
  u32 u = __builtin_bit_cast(u32, f);
  u32 r = u + 0x7fffu + ((u >> 16) & 1u);
  return (u16)(r >> 16);
}
__device__ __forceinline__ float bf2f(u16 u) {
  return __builtin_bit_cast(float, (u32)u << 16);
}

__device__ __forceinline__ f32x4 mfma16(short8 a, short8 b, f32x4 c) {
  return __builtin_amdgcn_mfma_f32_16x16x32_bf16(
      __builtin_bit_cast(bf16x8, a), __builtin_bit_cast(bf16x8, b), c, 0, 0, 0);
}

__device__ __forceinline__ void gload16(const u16* g, u16* l) {
  __builtin_amdgcn_global_load_lds((gu16*)g, (lu16*)l, 16, 0, 0);
}

__device__ __forceinline__ u32 cvtpk(float lo, float hi) {
  u32 r;
  asm("v_cvt_pk_bf16_f32 %0, %1, %2" : "=v"(r) : "v"(lo), "v"(hi));
  return r;
}

// ---------------- fp32 -> bf16 elementwise ----------------
__global__ __launch_bounds__(256) void k_cvt_bf16(const float* __restrict__ in,
                                                  u16* __restrict__ out, int n) {
  int i = (blockIdx.x * 256 + threadIdx.x) * 8;
  if (i >= n) return;
  float4 a = *(const float4*)(in + i);
  float4 b = *(const float4*)(in + i + 4);
  ushort8 o;
  o[0] = f2bf(a.x); o[1] = f2bf(a.y); o[2] = f2bf(a.z); o[3] = f2bf(a.w);
  o[4] = f2bf(b.x); o[5] = f2bf(b.y); o[6] = f2bf(b.z); o[7] = f2bf(b.w);
  *(ushort8*)(out + i) = o;
}

// ---------------- fp32 [R][C] -> bf16 [C][R] (generic weight transpose) ----------
__global__ __launch_bounds__(256) void k_transpose_w(const float* __restrict__ in,
                                                     u16* __restrict__ out, int R, int C,
                                                     float scale) {
  __shared__ float t[32][33];
  int c0 = blockIdx.x * 32, r0 = blockIdx.y * 32;
  int tx = threadIdx.x & 31, ty = threadIdx.x >> 5;
#pragma unroll
  for (int i = 0; i < 4; ++i)
    t[ty + i * 8][tx] = in[(r0 + ty + i * 8) * C + c0 + tx];
  __syncthreads();
#pragma unroll
  for (int i = 0; i < 4; ++i)
    out[(c0 + ty + i * 8) * R + r0 + tx] = f2bf(t[tx][ty + i * 8] * scale);
}

// ------- fused transpose of the four 1024x1024 weights (Wq|Wk|Wv|Wo, z-indexed) ---
// outputs are contiguous: WqkvT (3x 1M) then WoT (1M). Wq gets QSCALE folded in.
__global__ __launch_bounds__(256) void k_transpose_w4(
    const float* __restrict__ W0, const float* __restrict__ W1,
    const float* __restrict__ W2, const float* __restrict__ W3,
    u16* __restrict__ out) {
  __shared__ float t[32][33];
  int z = blockIdx.z;
  const float* in = (z == 0) ? W0 : (z == 1 ? W1 : (z == 2 ? W2 : W3));
  float scale = (z == 0) ? QSCALE : 1.f;
  u16* o = out + z * 1024 * 1024;
  int c0 = blockIdx.x * 32, r0 = blockIdx.y * 32;
  int tx = threadIdx.x & 31, ty = threadIdx.x >> 5;
#pragma unroll
  for (int i = 0; i < 4; ++i)
    t[ty + i * 8][tx] = in[(r0 + ty + i * 8) * 1024 + c0 + tx];
  __syncthreads();
#pragma unroll
  for (int i = 0; i < 4; ++i)
    o[(c0 + ty + i * 8) * 1024 + r0 + tx] = f2bf(t[tx][ty + i * 8] * scale);
}

// ---------------- prep: bias concat [bq*QSCALE | bk | bv] + mask -> float bias ----
__global__ void k_prep(const float* __restrict__ bq, const float* __restrict__ bk,
                       const float* __restrict__ bv, float* __restrict__ bcat,
                       const int* __restrict__ m, float* __restrict__ mf) {
  int i = blockIdx.x * 256 + threadIdx.x;
  if (i < 3072) {
    float v = (i < 1024) ? bq[i] * QSCALE : (i < 2048 ? bk[i - 1024] : bv[i - 2048]);
    bcat[i] = v;
  }
  if (i < BATCH * S_LEN) mf[i] = m[i] ? -1e30f : 0.f;
}

// ---------------- bf16 V (inside qkvb, col offset 2048) -> vT [b][h][d][s] -------
__global__ void k_transpose_v(const u16* __restrict__ qkvb, u16* __restrict__ vT) {
  __shared__ u16 t[64][65];
  int s0 = blockIdx.x * 64;
  int bh = blockIdx.y;           // b*NHEAD + h
  int b = bh >> 4, h = bh & 15;
  int tx = threadIdx.x, ty = threadIdx.y;  // (64,4)
#pragma unroll
  for (int i = 0; i < 16; ++i) {
    int s = i * 4 + ty;
    t[s][tx] = qkvb[((s0 + s) * BATCH + b) * QKV_N + 2048 + h * HDIM + tx];
  }
  __syncthreads();
#pragma unroll
  for (int i = 0; i < 16; ++i) {
    int d = i * 4 + ty;
    vT[(bh * HDIM + d) * S_LEN + s0 + tx] = t[tx][d];
  }
}

// ---------------- 128x128 GEMM, BK=32, dbuf, swizzled, 2-phase, split-K ----------
// (s_setprio removed: m190 measured it slightly harmful in lockstep-wave GEMMs)
template <int NS, bool RELU>
__global__ __launch_bounds__(256, 4) void k_gemm128(
    const u16* __restrict__ A, const u16* __restrict__ Bt,
    const float* __restrict__ bias, u16* __restrict__ C,
    u16* __restrict__ P1, u16* __restrict__ P2, u16* __restrict__ P3,
    int M, int N, int K, int nbx) {
  __shared__ u16 As[2][128 * 32];
  __shared__ u16 Bs[2][128 * 32];
  int tid = threadIdx.x;
  int lane = tid & 63;
  int lm = lane & 15, lg = lane >> 4;
  int w = tid >> 6;
  int wm = w >> 1, wn = w & 1;      // 2x2 waves; wave tile 64x64

  int cpx = gridDim.x >> 3;
  int nw = (blockIdx.x & 7) * cpx + (blockIdx.x >> 3);
  int nb = gridDim.x / NS;
  int slice = nw / nb;
  int t0 = nw - slice * nb;
  int m0 = (t0 / nbx) * 128, n0 = (t0 % nbx) * 128;
  int klen = K / NS, koff = slice * klen;

  f32x4 z = {0.f, 0.f, 0.f, 0.f};
  f32x4 acc[4][4];
#pragma unroll
  for (int mi = 0; mi < 4; ++mi)
#pragma unroll
    for (int ni = 0; ni < 4; ++ni) acc[mi][ni] = z;

  const u16* aSrc[2];
  const u16* bSrc[2];
  int dOff[2];
#pragma unroll
  for (int i = 0; i < 2; ++i) {
    int ci = i * 256 + tid;
    int row = ci >> 2, ch = ci & 3;
    int sc = 8 * (ch ^ ((row >> 1) & 3));
    aSrc[i] = A + (m0 + row) * K + koff + sc;
    bSrc[i] = Bt + (n0 + row) * K + koff + sc;
    dOff[i] = ci * 8;
  }

  auto stage = [&](int buf, int k0) {
#pragma unroll
    for (int i = 0; i < 2; ++i) {
      gload16(aSrc[i] + k0, &As[buf][0] + dOff[i]);
      gload16(bSrc[i] + k0, &Bs[buf][0] + dOff[i]);
    }
  };

  int swz = (lm >> 1) & 3;
  int nkt = klen >> 5;
  stage(0, 0);
  __syncthreads();
  for (int t = 0; t < nkt; ++t) {
    int cur = t & 1;
    if (t + 1 < nkt) stage(cur ^ 1, (t + 1) << 5);
    const u16* Ab = &As[cur][0];
    const u16* Bb = &Bs[cur][0];
    short8 bf[4];
#pragma unroll
    for (int ni = 0; ni < 4; ++ni) {
      int row = wn * 64 + ni * 16 + lm;
      bf[ni] = *(const short8*)(Bb + row * 32 + 8 * (lg ^ swz));
    }
#pragma unroll
    for (int mi = 0; mi < 4; ++mi) {
      int row = wm * 64 + mi * 16 + lm;
      short8 af = *(const short8*)(Ab + row * 32 + 8 * (lg ^ swz));
#pragma unroll
      for (int ni = 0; ni < 4; ++ni)
        acc[mi][ni] = mfma16(af, bf[ni], acc[mi][ni]);
    }
    __syncthreads();
  }

  u16* Cout = C;
  if (NS > 1) Cout = (slice == 0) ? C : (slice == 1 ? P1 : (slice == 2 ? P2 : P3));
#pragma unroll
  for (int ni = 0; ni < 4; ++ni) {
    int c = n0 + wn * 64 + ni * 16 + lm;
    float bc = (NS == 1) ? bias[c] : 0.f;
#pragma unroll
    for (int mi = 0; mi < 4; ++mi) {
#pragma unroll
      for (int j = 0; j < 4; ++j) {
        int r = m0 + wm * 64 + mi * 16 + lg * 4 + j;
        float x = acc[mi][ni][j] + bc;
        if (RELU) x = fmaxf(x, 0.f);
        Cout[r * N + c] = f2bf(x);
      }
    }
  }
}

// ---- reduce 4 bf16 partials + bias + resid (f32 or bf16), then layernorm --------
template <bool RF32, bool OUTF>
__global__ __launch_bounds__(256) void k_reduce_ln(
    const u16* __restrict__ P0, const u16* __restrict__ P1,
    const u16* __restrict__ P2, const u16* __restrict__ P3,
    const float* __restrict__ bias, const float* __restrict__ residf,
    const u16* __restrict__ residb, const float* __restrict__ gam,
    const float* __restrict__ bet, float* __restrict__ outf,
    u16* __restrict__ outb) {
  int r = blockIdx.x;
  int tid = threadIdx.x;
  int c4 = tid * 4;
  int idx = r * EMB + c4;
  u16x4 a0 = *(const u16x4*)(P0 + idx);
  u16x4 a1 = *(const u16x4*)(P1 + idx);
  u16x4 a2 = *(const u16x4*)(P2 + idx);
  u16x4 a3 = *(const u16x4*)(P3 + idx);
  float4 bi = *(const float4*)(bias + c4);
  float4 rs;
  if (RF32) {
    rs = *(const float4*)(residf + idx);
  } else {
    u16x4 rb = *(const u16x4*)(residb + idx);
    rs.x = bf2f(rb[0]); rs.y = bf2f(rb[1]); rs.z = bf2f(rb[2]); rs.w = bf2f(rb[3]);
  }
  float4 v;
  v.x = bf2f(a0[0]) + bf2f(a1[0]) + bf2f(a2[0]) + bf2f(a3[0]) + bi.x + rs.x;
  v.y = bf2f(a0[1]) + bf2f(a1[1]) + bf2f(a2[1]) + bf2f(a3[1]) + bi.y + rs.y;
  v.z = bf2f(a0[2]) + bf2f(a1[2]) + bf2f(a2[2]) + bf2f(a3[2]) + bi.z + rs.z;
  v.w = bf2f(a0[3]) + bf2f(a1[3]) + bf2f(a2[3]) + bf2f(a3[3]) + bi.w + rs.w;
  float s = v.x + v.y + v.z + v.w;
  float ss = v.x * v.x + v.y * v.y + v.z * v.z + v.w * v.w;
#pragma unroll
  for (int off = 1; off < 64; off <<= 1) {
    s += __shfl_xor(s, off);
    ss += __shfl_xor(ss, off);
  }
  __shared__ float red[2][4];
  int w = tid >> 6, lane = tid & 63;
  if (lane == 0) { red[0][w] = s; red[1][w] = ss; }
  __syncthreads();
  s = red[0][0] + red[0][1] + red[0][2] + red[0][3];
  ss = red[1][0] + red[1][1] + red[1][2] + red[1][3];
  float mean = s * (1.f / EMB);
  float var = ss * (1.f / EMB) - mean * mean;
  float inv = rsqrtf(var + 1e-5f);
  float4 g = *(const float4*)(gam + c4);
  float4 be = *(const float4*)(bet + c4);
  float4 o;
  o.x = (v.x - mean) * inv * g.x + be.x;
  o.y = (v.y - mean) * inv * g.y + be.y;
  o.z = (v.z - mean) * inv * g.z + be.z;
  o.w = (v.w - mean) * inv * g.w + be.w;
  if (OUTF) {
    *(float4*)(outf + idx) = o;
  } else {
    u16 ob[4] = {f2bf(o.x), f2bf(o.y), f2bf(o.z), f2bf(o.w)};
    *(u16x4*)(outb + idx) = *(u16x4*)ob;
  }
}

// ---------------- flash attention v7 (proven): 2 query-tiles, b64 P store -------
__global__ __launch_bounds__(256) void k_attn(
    const u16* __restrict__ qkvb, const u16* __restrict__ vT,
    const float* __restrict__ maskf, u16* __restrict__ outb) {
  __shared__ u16 Kl[2][4096];
  __shared__ u16 Vl[2][4096];
  __shared__ u16 Pl[4][2048];            // per wave: 2 swizzled 16x64 P tiles
  int tid = threadIdx.x;
  int lane = tid & 63, w = tid >> 6;
  int lm = lane & 15, lg = lane >> 4;
  int L = blockIdx.x;                    // 0..511
  int bh = (L & 7) + 8 * (L >> 7);       // xcd-contiguous per (b,h); bijective
  int qi0 = ((L >> 3) & 15) * 128;
  int b = bh >> 4, h = bh & 15;

  short8 qf0[2], qf1[2];
#pragma unroll
  for (int qt = 0; qt < 2; ++qt) {
    int qs = qi0 + qt * 64 + w * 16 + lm;
    const u16* qp = qkvb + (qs * BATCH + b) * QKV_N + h * HDIM;
    qf0[qt] = *(const short8*)(qp + lg * 8);
    qf1[qt] = *(const short8*)(qp + 32 + lg * 8);
  }

  // staging: wave-uniform dests, per-lane pre-swizzled source (proven v4 pattern)
  int r0 = tid >> 3, c8 = tid & 7;
  int swz8 = 8 * (c8 ^ (r0 & 7));
  const u16* kA = qkvb + (r0 * BATCH + b) * QKV_N + 1024 + h * HDIM + swz8;
  const u16* kB = qkvb + ((r0 + 32) * BATCH + b) * QKV_N + 1024 + h * HDIM + swz8;
  const u16* vA = vT + (bh * HDIM + r0) * S_LEN + swz8;
  const u16* vB = vT + (bh * HDIM + r0 + 32) * S_LEN + swz8;
  const int KSTEP = 64 * BATCH * QKV_N;

  const float* mp = maskf + b * S_LEN;

  u16* Pw = Pl[w];
  int rd_swz = (lm & 7) << 3;
  const u16* prd0 = Pw + lm * 64 + ((lg * 8) ^ rd_swz);
  const u16* prd1 = Pw + lm * 64 + ((32 + lg * 8) ^ rd_swz);
  u16* pwr[4];
#pragma unroll
  for (int ni = 0; ni < 4; ++ni)
    pwr[ni] = Pw + lm * 64 + ((ni * 16 + lg * 4) ^ rd_swz);

  f32x4 z = {0.f, 0.f, 0.f, 0.f};
  f32x4 o[2][4] = {{z, z, z, z}, {z, z, z, z}};
  float lrow[2] = {0.f, 0.f};
  float4 mk[4], mknext[4];

  {
    u16* kd = Kl[0] + w * 512;
    u16* vd = Vl[0] + w * 512;
    gload16(kA, kd); gload16(kB, kd + 2048);
    gload16(vA, vd); gload16(vB, vd + 2048);
    kA += KSTEP; kB += KSTEP; vA += 64; vB += 64;
#pragma unroll
    for (int ni = 0; ni < 4; ++ni)
      mk[ni] = *(const float4*)(mp + ni * 16 + lg * 4);
  }
  __syncthreads();

  int cur = 0;
  for (int kt = 0; kt < S_LEN; kt += 64) {
    if (kt + 64 < S_LEN) {
      u16* kd = Kl[cur ^ 1] + w * 512;
      u16* vd = Vl[cur ^ 1] + w * 512;
      gload16(kA, kd); gload16(kB, kd + 2048);
      gload16(vA, vd); gload16(vB, vd + 2048);
      kA += KSTEP; kB += KSTEP; vA += 64; vB += 64;
#pragma unroll
      for (int ni = 0; ni < 4; ++ni)
        mknext[ni] = *(const float4*)(mp + kt + 64 + ni * 16 + lg * 4);
    }
    const u16* Kc = Kl[cur];
    const u16* Vc = Vl[cur];
#pragma unroll
    for (int ni = 0; ni < 4; ++ni) {
      const u16* kl = Kc + (ni * 16 + lm) * 64;
      short8 k0 = *(const short8*)(kl + ((lg * 8) ^ rd_swz));
      short8 k1 = *(const short8*)(kl + ((32 + lg * 8) ^ rd_swz));
      float4 mb = mk[ni];
#pragma unroll
      for (int qt = 0; qt < 2; ++qt) {
        // swapped: rows = keys (ni*16+lg*4+j), col = query lm; exp2 domain
        f32x4 t = mfma16(k0, qf0[qt], z);
        f32x4 sv = mfma16(k1, qf1[qt], t);
        float p0 = __builtin_amdgcn_exp2f(sv[0] + mb.x);
        float p1 = __builtin_amdgcn_exp2f(sv[1] + mb.y);
        float p2 = __builtin_amdgcn_exp2f(sv[2] + mb.z);
        float p3 = __builtin_amdgcn_exp2f(sv[3] + mb.w);
        lrow[qt] += (p0 + p1) + (p2 + p3);
        u32x2 pk;
        pk[0] = cvtpk(p0, p1);
        pk[1] = cvtpk(p2, p3);
        *(u32x2*)(pwr[ni] + qt * 1024) = pk;   // ds_write_b64: 4 keys packed
      }
    }
    short8 pa0[2], pa1[2];
#pragma unroll
    for (int qt = 0; qt < 2; ++qt) {
      pa0[qt] = *(const short8*)(prd0 + qt * 1024);
      pa1[qt] = *(const short8*)(prd1 + qt * 1024);
    }
#pragma unroll
    for (int ni = 0; ni < 4; ++ni) {
      const u16* vl = Vc + (ni * 16 + lm) * 64;
      short8 v0 = *(const short8*)(vl + ((lg * 8) ^ rd_swz));
      short8 v1 = *(const short8*)(vl + ((32 + lg * 8) ^ rd_swz));
#pragma unroll
      for (int qt = 0; qt < 2; ++qt) {
        o[qt][ni] = mfma16(pa0[qt], v0, o[qt][ni]);
        o[qt][ni] = mfma16(pa1[qt], v1, o[qt][ni]);
      }
    }
#pragma unroll
    for (int ni = 0; ni < 4; ++ni) mk[ni] = mknext[ni];
    __syncthreads();
    cur ^= 1;
  }

#pragma unroll
  for (int qt = 0; qt < 2; ++qt) {
    float l = lrow[qt];
    l += __shfl_xor(l, 16);
    l += __shfl_xor(l, 32);
    float inv = 1.f / l;
    float invj[4];
#pragma unroll
    for (int j = 0; j < 4; ++j) invj[j] = __shfl(inv, lg * 4 + j);
#pragma unroll
    for (int ni = 0; ni < 4; ++ni) {
      int c = h * HDIM + ni * 16 + lm;
#pragma unroll
      for (int j = 0; j < 4; ++j) {
        int srow = qi0 + qt * 64 + w * 16 + lg * 4 + j;
        outb[(srow * BATCH + b) * EMB + c] = f2bf(o[qt][ni][j] * invj[j]);
      }
    }
  }
}

extern "C" void kernel_launch(void* const* d_in, const int* in_sizes, int n_in,
                              void* d_out, int out_size, void* d_ws, size_t ws_size,
                              hipStream_t stream) {
  (void)in_sizes; (void)n_in; (void)out_size; (void)ws_size;
  const float* x = (const float*)d_in[0];
  const int* mask = (const int*)d_in[1];
  const float* Wq = (const float*)d_in[2];
  const float* bq = (const float*)d_in[3];
  const float* Wk = (const float*)d_in[4];
  const float* bk = (const float*)d_in[5];
  const float* Wv = (const float*)d_in[6];
  const float* bv = (const float*)d_in[7];
  const float* Wo = (const float*)d_in[8];
  const float* bo = (const float*)d_in[9];
  const float* g1 = (const float*)d_in[10];
  const float* be1 = (const float*)d_in[11];
  const float* W1 = (const float*)d_in[12];
  const float* b1 = (const float*)d_in[13];
  const float* W2 = (const float*)d_in[14];
  const float* b2 = (const float*)d_in[15];
  const float* g2 = (const float*)d_in[16];
  const float* be2 = (const float*)d_in[17];
  float* out = (float*)d_out;

  // workspace layout (109.1 MB):
  // [0, 8.4M)        xb -> vT -> PP0
  // [8.4M, 33.5M)    weights: WqkvT | WoT | W1T | W2T
  // [33.5M, 58.7M)   qkvb --\  f1b spans [33.5M, 67.1M)
  // [58.7M, 67.1M)   ao ----/
  // [67.1M, +32K)    bcat (12K) + maskf (16K)
  // [67.1M+64K, ..)  PP1 (8.4M)
  // [83.9M, 92.3M)   hb (bf16 LN1 out; FFN1 A; FFN2 resid)
  // [92.3M, 100.7M)  PP2
  // [100.7M, 109.1M) PP3
  char* p = (char*)d_ws;
  u16* xb = (u16*)(p);
  u16* WqkvT = (u16*)(p + 8388608);
  u16* WoT = WqkvT + 3 * 1024 * 1024;
  u16* W1T = WoT + 1024 * 1024;
  u16* W2T = W1T + 1024 * 4096;
  u16* qkvb = (u16*)(p + 33554432);
  u16* ao = (u16*)(p + 58720256);
  float* bcat = (float*)(p + 67108864);
  float* maskf = (float*)(p + 67108864 + 16384);
  u16* PP1 = (u16*)(p + 67108864 + 65536);
  u16* hb = (u16*)(p + 83886080);
  u16* vT = xb;
  u16* f1b = qkvb;
  u16* PP0 = xb;
  u16* PP2 = (u16*)(p + 92274688);
  u16* PP3 = (u16*)(p + 100663296);

  // conversions / transposes / prep
  k_cvt_bf16<<<NTOK * EMB / 2048, 256, 0, stream>>>(x, xb, NTOK * EMB);
  k_transpose_w4<<<dim3(32, 32, 4), 256, 0, stream>>>(Wq, Wk, Wv, Wo, WqkvT);
  k_transpose_w<<<dim3(128, 32), 256, 0, stream>>>(W1, W1T, 1024, 4096, 1.f);
  k_transpose_w<<<dim3(32, 128), 256, 0, stream>>>(W2, W2T, 4096, 1024, 1.f);
  k_prep<<<16, 256, 0, stream>>>(bq, bk, bv, bcat, mask, maskf);

  // fused QKV projection: grid 768 (3 blocks/CU)
  k_gemm128<1, false><<<(NTOK / 128) * (QKV_N / 128), 256, 0, stream>>>(
      xb, WqkvT, bcat, qkvb, nullptr, nullptr, nullptr, NTOK, QKV_N, EMB, QKV_N / 128);

  // V transpose, attention (512 blocks, 128 queries each)
  k_transpose_v<<<dim3(S_LEN / 64, BATCH * NHEAD), dim3(64, 4), 0, stream>>>(qkvb, vT);
  k_attn<<<512, 256, 0, stream>>>(qkvb, vT, maskf, ao);

  // O-proj split-K=4, then fused reduce + f32 resid(x) + LN1 -> hb (bf16 only)
  k_gemm128<4, false><<<(NTOK / 128) * (EMB / 128) * 4, 256, 0, stream>>>(
      ao, WoT, nullptr, PP0, PP1, PP2, PP3, NTOK, EMB, EMB, EMB / 128);
  k_reduce_ln<true, false><<<NTOK, 256, 0, stream>>>(
      PP0, PP1, PP2, PP3, bo, x, nullptr, g1, be1, nullptr, hb);

  // FFN1 (grid 1024, relu, bf16 out)
  k_gemm128<1, true><<<(NTOK / 128) * (FFN_DIM / 128), 256, 0, stream>>>(
      hb, W1T, b1, f1b, nullptr, nullptr, nullptr, NTOK, FFN_DIM, EMB, FFN_DIM / 128);

  // FFN2 split-K=4, then fused reduce + bf16 resid(hb) + LN2 -> out (f32)
  k_gemm128<4, false><<<(NTOK / 128) * (EMB / 128) * 4, 256, 0, stream>>>(
      f1b, W2T, nullptr, PP0, PP1, PP2, PP3, NTOK, EMB, FFN_DIM, EMB / 128);
  k_reduce_ln<false, true><<<NTOK, 256, 0, stream>>>(
      PP0, PP1, PP2, PP3, b2, nullptr, hb, g2, be2, out, nullptr);
}